// Round 1
// baseline (440.031 us; speedup 1.0000x reference)
//
#include <hip/hip_runtime.h>

// IndRNN recurrence: h_t = relu(h_{t-1} * w + x_t) elementwise over (B,H),
// sequential over T. One thread per (b,h) element; coalesced t-strided
// streaming of x (read) and h (write). Memory-bound: 512 MiB total traffic,
// ~85 us floor at 6.3 TB/s.

#define T_DIM 1024
#define B_DIM 64
#define H_DIM 1024
#define BH (B_DIM * H_DIM)

__global__ __launch_bounds__(256) void indrnn_kernel(
    const float* __restrict__ x,      // [T, B, H]
    const float* __restrict__ w,      // [H]
    const float* __restrict__ h0,     // [B, H]
    float* __restrict__ out)          // [T, B, H]
{
    const int idx = blockIdx.x * blockDim.x + threadIdx.x;  // b*H + h
    const float wv = w[idx & (H_DIM - 1)];
    float h = h0[idx];
    const float* xp = x + idx;
    float* op = out + idx;
    // x loads are independent across t; only the fma->max chain is serial.
    // unroll 16 keeps ~16 loads in flight per lane for latency hiding at
    // the fixed 4 waves/CU occupancy (65536 threads total).
    #pragma unroll 16
    for (int t = 0; t < T_DIM; ++t) {
        float xv = xp[(size_t)t * BH];
        h = fmaxf(fmaf(h, wv, xv), 0.0f);
        op[(size_t)t * BH] = h;
    }
}

extern "C" void kernel_launch(void* const* d_in, const int* in_sizes, int n_in,
                              void* d_out, int out_size, void* d_ws, size_t ws_size,
                              hipStream_t stream) {
    const float* x  = (const float*)d_in[0];
    const float* w  = (const float*)d_in[1];
    const float* h0 = (const float*)d_in[2];
    float* out = (float*)d_out;
    indrnn_kernel<<<BH / 256, 256, 0, stream>>>(x, w, h0, out);
}

// Round 2
// 426.807 us; speedup vs baseline: 1.0310x; 1.0310x over previous
//
#include <hip/hip_runtime.h>

// IndRNN recurrence: h_t = relu(h_{t-1} * w + x_t) elementwise over (B,H),
// sequential over T. One thread per (b,h); coalesced t-strided streaming.
// Memory-bound: 512 MiB total traffic, ~85 us floor at 6.3 TB/s achievable.
//
// R1: round-0 kernel ran at 1030 cyc/t-step == one serial HBM latency per
// iteration (compiler didn't batch loads despite unroll-16). Fix: explicit
// double-buffered register prefetch windows so ~16 loads/lane stay in
// flight (16 KB/CU > ~9 KB needed to cover ~900 cyc latency at 10 B/cyc/CU).

#define T_DIM 1024
#define B_DIM 64
#define H_DIM 1024
#define BH (B_DIM * H_DIM)
#define W 16   // prefetch window; 16 loads + 16 stores + 16 next loads = 48 < vmcnt cap 63

__global__ __launch_bounds__(256) void indrnn_kernel(
    const float* __restrict__ x,      // [T, B, H]
    const float* __restrict__ w,      // [H]
    const float* __restrict__ h0,     // [B, H]
    float* __restrict__ out)          // [T, B, H]
{
    const int idx = blockIdx.x * 256 + threadIdx.x;  // b*H + h
    const float wv = w[idx & (H_DIM - 1)];
    float h = h0[idx];
    const float* xp = x + idx;
    float* op = out + idx;

    float buf[W];
    #pragma unroll
    for (int i = 0; i < W; ++i) buf[i] = xp[(size_t)i * BH];

    for (int t0 = 0; t0 < T_DIM; t0 += W) {
        // Prefetch window t0+W while window t0 is consumed. Last iteration
        // re-reads window 0 (dead result, L3-hot) to stay branch-free/in-bounds.
        const int tp = (t0 + W < T_DIM) ? (t0 + W) : 0;
        float nbuf[W];
        #pragma unroll
        for (int i = 0; i < W; ++i) nbuf[i] = xp[(size_t)(tp + i) * BH];

        #pragma unroll
        for (int i = 0; i < W; ++i) {
            h = fmaxf(fmaf(h, wv, buf[i]), 0.0f);
            op[(size_t)(t0 + i) * BH] = h;
        }

        #pragma unroll
        for (int i = 0; i < W; ++i) buf[i] = nbuf[i];
    }
}

extern "C" void kernel_launch(void* const* d_in, const int* in_sizes, int n_in,
                              void* d_out, int out_size, void* d_ws, size_t ws_size,
                              hipStream_t stream) {
    const float* x  = (const float*)d_in[0];
    const float* w  = (const float*)d_in[1];
    const float* h0 = (const float*)d_in[2];
    float* out = (float*)d_out;
    indrnn_kernel<<<BH / 256, 256, 0, stream>>>(x, w, h0, out);
}